// Round 2
// baseline (583.408 us; speedup 1.0000x reference)
//
#include <hip/hip_runtime.h>
#include <cmath>

#define LN_EPS 1e-5f

typedef float  f32x4  __attribute__((ext_vector_type(4)));
typedef short  short8 __attribute__((ext_vector_type(8)));
typedef unsigned int uint4v __attribute__((ext_vector_type(4)));

// ws layout (bytes):
//   w1f  : 5*8*64*16 = 40960   (uint4 frags, B-operand layout, bf16)
//   w2f  : 4*8*64*16 = 32768
//   emb16: NUM_TYPES*128*2     (row-major bf16)
//   tps  : 5 floats (uniform temporal-LN closed-form sums)
#define W1F_U4 2560   // 5*8*64
#define W2F_U4 2048   // 4*8*64

__device__ __forceinline__ unsigned short f32_bf16_rne(float f) {
    union { float f; unsigned u; } v; v.f = f;
    unsigned r = v.u + 0x7FFFu + ((v.u >> 16) & 1u);
    return (unsigned short)(r >> 16);
}

// packed f32->bf16 (RNE), 1 VALU op for 2 elements
__device__ __forceinline__ unsigned cvt_pk_bf16(float lo, float hi) {
    unsigned r;
    asm("v_cvt_pk_bf16_f32 %0, %1, %2" : "=v"(r) : "v"(lo), "v"(hi));
    return r;
}

// exact-erf GELU via Abramowitz&Stegun 7.1.26 (|err| <= 1.5e-7)
__device__ __forceinline__ float gelu_f(float x) {
    float ax = fabsf(x);
    float a  = ax * 0.70710678118654752f;          // |x|/sqrt(2)
    float t  = __builtin_amdgcn_rcpf(fmaf(0.3275911f, a, 1.0f));
    float p  = t * fmaf(t, fmaf(t, fmaf(t, fmaf(t, 1.061405429f, -1.453152027f),
                                        1.421413741f), -0.284496736f), 0.254829592f);
    float e  = __builtin_amdgcn_exp2f(-1.44269504089f * a * a);
    float E  = fmaf(-p, e, 1.0f);                  // erf(|x|/sqrt2)
    return 0.5f * fmaf(ax, E, x);                  // 0.5*(x + |x|*erf)
}

// DPP row-rotate add: sum over the 16-lane DPP row, all lanes get the result.
template<int C>
__device__ __forceinline__ float dpp_radd(float x) {
    int t = __builtin_amdgcn_update_dpp(0, __builtin_bit_cast(int, x), C, 0xF, 0xF, true);
    return x + __builtin_bit_cast(float, t);
}
__device__ __forceinline__ float red16(float x) {
    x = dpp_radd<0x128>(x);   // row_ror:8
    x = dpp_radd<0x124>(x);   // row_ror:4
    x = dpp_radd<0x122>(x);   // row_ror:2
    x = dpp_radd<0x121>(x);   // row_ror:1
    return x;
}

// -------- prep: swizzle w1/w2 into MFMA B-fragment layout (bf16), convert emb
//          to bf16 rows, compute temporal-LN sums. Re-run every call.
__global__ void prep_kernel(const float* __restrict__ w1, const float* __restrict__ w2,
                            const float* __restrict__ emb,
                            const float* __restrict__ tp_w, const float* __restrict__ tp_b,
                            unsigned* __restrict__ ws, int emb_pairs) {
    const int tid = blockIdx.x * 256 + threadIdx.x;   // 8192 threads
    uint4v* w1f = (uint4v*)ws;
    uint4v* w2f = w1f + W1F_U4;
    unsigned* emb16 = (unsigned*)(w2f + W2F_U4);

    for (int i = tid; i < W1F_U4; i += 8192) {        // frag(kt,nt,lane): B[k][n]
        const int lane = i & 63, nt = (i >> 6) & 7, kt = i >> 9;
        const int k0 = kt * 32 + (lane >> 4) * 8, n = nt * 16 + (lane & 15);
        uint4v r;
        #pragma unroll
        for (int j2 = 0; j2 < 4; ++j2) {
            unsigned lo = f32_bf16_rne(w1[(k0 + 2 * j2) * 128 + n]);
            unsigned hi = f32_bf16_rne(w1[(k0 + 2 * j2 + 1) * 128 + n]);
            r[j2] = lo | (hi << 16);
        }
        w1f[i] = r;
    }
    for (int i = tid; i < W2F_U4; i += 8192) {
        const int lane = i & 63, nt = (i >> 6) & 7, kt = i >> 9;
        const int k0 = kt * 32 + (lane >> 4) * 8, n = nt * 16 + (lane & 15);
        uint4v r;
        #pragma unroll
        for (int j2 = 0; j2 < 4; ++j2) {
            unsigned lo = f32_bf16_rne(w2[(k0 + 2 * j2) * 128 + n]);
            unsigned hi = f32_bf16_rne(w2[(k0 + 2 * j2 + 1) * 128 + n]);
            r[j2] = lo | (hi << 16);
        }
        w2f[i] = r;
    }
    for (int i = tid; i < emb_pairs; i += 8192) {
        unsigned lo = f32_bf16_rne(emb[2 * i]);
        unsigned hi = f32_bf16_rne(emb[2 * i + 1]);
        emb16[i] = lo | (hi << 16);
    }
    if (tid == 0) {                                   // uniform temporal-LN sums
        float Sw = 0.f, Sb = 0.f, Sww = 0.f, Swb = 0.f, Sbb = 0.f;
        for (int j = 0; j < 32; ++j) {
            const float ww = tp_w[j], bb = tp_b[j];
            Sw += ww; Sb += bb; Sww += ww * ww; Swb += ww * bb; Sbb += bb * bb;
        }
        float* tps = (float*)(emb16 + emb_pairs);
        tps[0] = Sw; tps[1] = Sb; tps[2] = Sww; tps[3] = Swb; tps[4] = Sbb;
    }
}

// -------- main: one block per batch row. 4 waves loop over 16-row tiles
//          (t = w, w+4, ...): no early-exit waves, balanced, prologue amortized.
//          Pool accumulated in registers, combined via LDS -> ONE plain store
//          per row (zero atomics).
__global__ __launch_bounds__(256, 5) void encoder_mfma(
    const int*   __restrict__ tids,  const float* __restrict__ dates,
    const int*   __restrict__ lengths,
    const float* __restrict__ tp_w,  const float* __restrict__ tp_b,
    const float* __restrict__ tp_lnw,const float* __restrict__ tp_lnb,
    const float* __restrict__ b1,    const float* __restrict__ ln1w, const float* __restrict__ ln1b,
    const float* __restrict__ b2,    const float* __restrict__ ln2w, const float* __restrict__ ln2b,
    const unsigned* __restrict__ ws, float* __restrict__ out, int L, int emb_pairs)
{
    // per-wave C->A transpose scratch: [wave][kt2][row64 (XOR-swizzled)][j]
    __shared__ __align__(16) unsigned short a2[4][4][64][8];   // 16 KB
    __shared__ float poolbuf[4][128];                          // 2 KB

    const int b   = blockIdx.x;
    const int tid = threadIdx.x;
    const int lane = tid & 63, w = tid >> 6;
    const int c = lane & 15, g = lane >> 4;
    const int len = min(max(lengths[b], 0), L);
    const int ntiles = (len + 15) >> 4;               // 0..13

    const uint4v* w1f = (const uint4v*)ws;
    const uint4v* w2f = w1f + W1F_U4;
    const unsigned short* emb16 = (const unsigned short*)(w2f + W2F_U4);
    const float* tps = (const float*)(emb16 + emb_pairs * 2);
    const float Sw = tps[0], Sb = tps[1], Sww = tps[2], Swb = tps[3], Sbb = tps[4];

    // hoisted per-lane epilogue coefficients (col = nt*16 + c)
    float l1w[8], l1b[8], bb1[8], l2w[8], l2b[8], bb2[8], pool[8];
    #pragma unroll
    for (int nt = 0; nt < 8; ++nt) {
        const int col = nt * 16 + c;
        l1w[nt] = ln1w[col]; l1b[nt] = ln1b[col]; bb1[nt] = b1[col];
        l2w[nt] = ln2w[col]; l2b[nt] = ln2b[col]; bb2[nt] = b2[col];
        pool[nt] = 0.f;
    }
    const int srl = lane ^ ((lane >> 3) & 3);          // swizzled GEMM2 read row

    for (int t = w; t < ntiles; t += 4) {
        const int R0 = t << 4;
        const int pc = min(R0 + c, L - 1);
        const int id = tids[b * L + pc];
        const float d = dates[b * L + pc] * (1.f / 1825.f);

        // temporal A-frag (row = c, k-chunk = g*8..g*8+7)
        short8 tfrag;
        {
            const float tm = fmaf(d, Sw, Sb) * (1.f / 32.f);
            float tv = fmaf(d * d, Sww, fmaf(2.f * d, Swb, Sbb)) * (1.f / 32.f) - tm * tm;
            const float trs = rsqrtf(fmaxf(tv, 0.f) + LN_EPS);
            const int j0 = g * 8;
            uint4v r;
            #pragma unroll
            for (int j2 = 0; j2 < 4; ++j2) {
                const float w0 = tp_w[j0 + 2*j2],   bq0 = tp_b[j0 + 2*j2];
                const float w1v = tp_w[j0 + 2*j2+1], bq1 = tp_b[j0 + 2*j2+1];
                const float y0 = fmaf((fmaf(d, w0,  bq0) - tm) * trs, tp_lnw[j0 + 2*j2],   tp_lnb[j0 + 2*j2]);
                const float y1 = fmaf((fmaf(d, w1v, bq1) - tm) * trs, tp_lnw[j0 + 2*j2+1], tp_lnb[j0 + 2*j2+1]);
                r[j2] = cvt_pk_bf16(gelu_f(y0), gelu_f(y1));
            }
            union { uint4v u; short8 s; } cv; cv.u = r;
            tfrag = cv.s;
        }

        // ---------------- GEMM1: [16 x K=160] @ w1 ----------------
        f32x4 acc[8];
        #pragma unroll
        for (int nt = 0; nt < 8; ++nt) acc[nt] = (f32x4){0.f, 0.f, 0.f, 0.f};
        #pragma unroll
        for (int kt = 0; kt < 5; ++kt) {
            const short8 af = (kt < 4) ? *(const short8*)(emb16 + id * 128 + kt * 32 + g * 8)
                                       : tfrag;
            #pragma unroll
            for (int nt = 0; nt < 8; ++nt) {
                const short8 bf = ((const short8*)w1f)[(kt * 8 + nt) * 64 + lane];
                acc[nt] = __builtin_amdgcn_mfma_f32_16x16x32_bf16(af, bf, acc[nt], 0, 0, 0);
            }
        }

        // ------- epilogue 1: +b1, LN1 (DPP reduce), GELU -> bf16 a2 (swizzled) -------
        #pragma unroll
        for (int r = 0; r < 4; ++r) {
            float v[8], s = 0.f, q = 0.f;
            #pragma unroll
            for (int nt = 0; nt < 8; ++nt) {
                v[nt] = acc[nt][r] + bb1[nt];
                s += v[nt]; q = fmaf(v[nt], v[nt], q);
            }
            s = red16(s); q = red16(q);
            const float mean = s * (1.f / 128.f);
            const float var  = fmaxf(q * (1.f / 128.f) - mean * mean, 0.f);
            const float rstd = rsqrtf(var + LN_EPS);
            const int mrow = 4 * g + r;
            #pragma unroll
            for (int n2 = 0; n2 < 4; ++n2) {
                const float y0 = gelu_f(fmaf((v[2*n2]   - mean) * rstd, l1w[2*n2],   l1b[2*n2]));
                const float y1 = gelu_f(fmaf((v[2*n2+1] - mean) * rstd, l1w[2*n2+1], l1b[2*n2+1]));
                const unsigned pk = cvt_pk_bf16(y0, y1);
                {
                    const int kcol  = (2*n2) * 16 + c;
                    const int row64 = ((kcol >> 3) & 3) * 16 + mrow;
                    const int srow  = row64 ^ ((row64 >> 3) & 3);
                    a2[w][kcol >> 5][srow][kcol & 7] = (unsigned short)(pk & 0xffffu);
                }
                {
                    const int kcol  = (2*n2+1) * 16 + c;
                    const int row64 = ((kcol >> 3) & 3) * 16 + mrow;
                    const int srow  = row64 ^ ((row64 >> 3) & 3);
                    a2[w][kcol >> 5][srow][kcol & 7] = (unsigned short)(pk >> 16);
                }
            }
        }

        // wave-local LDS write->read ordering
        asm volatile("s_waitcnt lgkmcnt(0)" ::: "memory");
        __builtin_amdgcn_sched_barrier(0);

        // ---------------- GEMM2: a2 @ w2 ----------------
        f32x4 acc2[8];
        #pragma unroll
        for (int nt = 0; nt < 8; ++nt) acc2[nt] = (f32x4){0.f, 0.f, 0.f, 0.f};
        #pragma unroll
        for (int kt2 = 0; kt2 < 4; ++kt2) {
            short8 af;
            __builtin_memcpy(&af, &a2[w][kt2][srl][0], 16);
            #pragma unroll
            for (int nt = 0; nt < 8; ++nt) {
                const short8 bf = ((const short8*)w2f)[(kt2 * 8 + nt) * 64 + lane];
                acc2[nt] = __builtin_amdgcn_mfma_f32_16x16x32_bf16(af, bf, acc2[nt], 0, 0, 0);
            }
        }

        // ---------------- epilogue 2: +b2, LN2, mask, pool (registers) ----------------
        #pragma unroll
        for (int r = 0; r < 4; ++r) {
            float v[8], s = 0.f, q = 0.f;
            #pragma unroll
            for (int nt = 0; nt < 8; ++nt) {
                v[nt] = acc2[nt][r] + bb2[nt];
                s += v[nt]; q = fmaf(v[nt], v[nt], q);
            }
            s = red16(s); q = red16(q);
            const float mean = s * (1.f / 128.f);
            const float var  = fmaxf(q * (1.f / 128.f) - mean * mean, 0.f);
            const float rstd = rsqrtf(var + LN_EPS);
            const int p = R0 + 4 * g + r;
            const float msk = (p < len) ? 1.f : 0.f;
            #pragma unroll
            for (int nt = 0; nt < 8; ++nt) {
                const float y = fmaf((v[nt] - mean) * rstd, l2w[nt], l2b[nt]);
                pool[nt] = fmaf(y, msk, pool[nt]);
            }
        }
    }

    // wave-level pool reduce (over g groups), then cross-wave combine in LDS
    #pragma unroll
    for (int nt = 0; nt < 8; ++nt) {
        float tv = pool[nt];
        tv += __shfl_xor(tv, 16);
        tv += __shfl_xor(tv, 32);
        pool[nt] = tv;
    }
    if (g == 0) {
        #pragma unroll
        for (int nt = 0; nt < 8; ++nt) poolbuf[w][nt * 16 + c] = pool[nt];
    }
    __syncthreads();
    if (tid < 128) {
        const float s = poolbuf[0][tid] + poolbuf[1][tid] + poolbuf[2][tid] + poolbuf[3][tid];
        out[b * 128 + tid] = (len > 0) ? s / (float)len : 0.f;
    }
}

extern "C" void kernel_launch(void* const* d_in, const int* in_sizes, int n_in,
                              void* d_out, int out_size, void* d_ws, size_t ws_size,
                              hipStream_t stream) {
    const int*   tids    = (const int*)  d_in[0];
    const float* dates   = (const float*)d_in[1];
    const int*   lengths = (const int*)  d_in[2];
    const float* emb     = (const float*)d_in[3];
    const float* tp_w    = (const float*)d_in[4];
    const float* tp_b    = (const float*)d_in[5];
    const float* tp_lnw  = (const float*)d_in[6];
    const float* tp_lnb  = (const float*)d_in[7];
    const float* w1      = (const float*)d_in[8];
    const float* b1      = (const float*)d_in[9];
    const float* ln1w    = (const float*)d_in[10];
    const float* ln1b    = (const float*)d_in[11];
    const float* w2      = (const float*)d_in[12];
    const float* b2      = (const float*)d_in[13];
    const float* ln2w    = (const float*)d_in[14];
    const float* ln2b    = (const float*)d_in[15];
    float* out = (float*)d_out;

    const int B = in_sizes[2];
    const int L = in_sizes[0] / B;
    const int emb_pairs = in_sizes[3] / 2;

    hipLaunchKernelGGL(prep_kernel, dim3(32), dim3(256), 0, stream,
                       w1, w2, emb, tp_w, tp_b, (unsigned*)d_ws, emb_pairs);
    hipLaunchKernelGGL(encoder_mfma, dim3(B), dim3(256), 0, stream,
                       tids, dates, lengths, tp_w, tp_b, tp_lnw, tp_lnb,
                       b1, ln1w, ln1b, b2, ln2w, ln2b,
                       (const unsigned*)d_ws, out, L, emb_pairs);
}

// Round 3
// 546.767 us; speedup vs baseline: 1.0670x; 1.0670x over previous
//
#include <hip/hip_runtime.h>
#include <cmath>

#define LN_EPS 1e-5f

typedef float  f32x4  __attribute__((ext_vector_type(4)));
typedef short  short8 __attribute__((ext_vector_type(8)));
typedef unsigned int uint4v __attribute__((ext_vector_type(4)));

// ws layout (bytes):
//   w1f  : 5*8*64*16 = 40960   (uint4 frags, B-operand layout, bf16)
//   w2f  : 4*8*64*16 = 32768
//   emb16: NUM_TYPES*128*2     (row-major bf16)
//   tps  : 5 floats (uniform temporal-LN closed-form sums)
#define W1F_U4 2560   // 5*8*64
#define W2F_U4 2048   // 4*8*64

__device__ __forceinline__ unsigned short f32_bf16_rne(float f) {
    union { float f; unsigned u; } v; v.f = f;
    unsigned r = v.u + 0x7FFFu + ((v.u >> 16) & 1u);
    return (unsigned short)(r >> 16);
}

// packed f32->bf16 (RNE), 1 VALU op for 2 elements
__device__ __forceinline__ unsigned cvt_pk_bf16(float lo, float hi) {
    unsigned r;
    asm("v_cvt_pk_bf16_f32 %0, %1, %2" : "=v"(r) : "v"(lo), "v"(hi));
    return r;
}

// exact-erf GELU via Abramowitz&Stegun 7.1.26 (|err| <= 1.5e-7)
__device__ __forceinline__ float gelu_f(float x) {
    float ax = fabsf(x);
    float a  = ax * 0.70710678118654752f;          // |x|/sqrt(2)
    float t  = __builtin_amdgcn_rcpf(fmaf(0.3275911f, a, 1.0f));
    float p  = t * fmaf(t, fmaf(t, fmaf(t, fmaf(t, 1.061405429f, -1.453152027f),
                                        1.421413741f), -0.284496736f), 0.254829592f);
    float e  = __builtin_amdgcn_exp2f(-1.44269504089f * a * a);
    float E  = fmaf(-p, e, 1.0f);                  // erf(|x|/sqrt2)
    return 0.5f * fmaf(ax, E, x);                  // 0.5*(x + |x|*erf)
}

// DPP row-rotate add: sum over the 16-lane DPP row, all lanes get the result.
template<int C>
__device__ __forceinline__ float dpp_radd(float x) {
    int t = __builtin_amdgcn_update_dpp(0, __builtin_bit_cast(int, x), C, 0xF, 0xF, true);
    return x + __builtin_bit_cast(float, t);
}
__device__ __forceinline__ float red16(float x) {
    x = dpp_radd<0x128>(x);   // row_ror:8
    x = dpp_radd<0x124>(x);   // row_ror:4
    x = dpp_radd<0x122>(x);   // row_ror:2
    x = dpp_radd<0x121>(x);   // row_ror:1
    return x;
}

// -------- prep: swizzle w1/w2 into MFMA B-fragment layout (bf16), convert emb
//          to bf16 rows, compute temporal-LN sums. Re-run every call.
__global__ void prep_kernel(const float* __restrict__ w1, const float* __restrict__ w2,
                            const float* __restrict__ emb,
                            const float* __restrict__ tp_w, const float* __restrict__ tp_b,
                            unsigned* __restrict__ ws, int emb_pairs) {
    const int tid = blockIdx.x * 256 + threadIdx.x;   // 8192 threads
    uint4v* w1f = (uint4v*)ws;
    uint4v* w2f = w1f + W1F_U4;
    unsigned* emb16 = (unsigned*)(w2f + W2F_U4);

    for (int i = tid; i < W1F_U4; i += 8192) {        // frag(kt,nt,lane): B[k][n]
        const int lane = i & 63, nt = (i >> 6) & 7, kt = i >> 9;
        const int k0 = kt * 32 + (lane >> 4) * 8, n = nt * 16 + (lane & 15);
        uint4v r;
        #pragma unroll
        for (int j2 = 0; j2 < 4; ++j2) {
            unsigned lo = f32_bf16_rne(w1[(k0 + 2 * j2) * 128 + n]);
            unsigned hi = f32_bf16_rne(w1[(k0 + 2 * j2 + 1) * 128 + n]);
            r[j2] = lo | (hi << 16);
        }
        w1f[i] = r;
    }
    for (int i = tid; i < W2F_U4; i += 8192) {
        const int lane = i & 63, nt = (i >> 6) & 7, kt = i >> 9;
        const int k0 = kt * 32 + (lane >> 4) * 8, n = nt * 16 + (lane & 15);
        uint4v r;
        #pragma unroll
        for (int j2 = 0; j2 < 4; ++j2) {
            unsigned lo = f32_bf16_rne(w2[(k0 + 2 * j2) * 128 + n]);
            unsigned hi = f32_bf16_rne(w2[(k0 + 2 * j2 + 1) * 128 + n]);
            r[j2] = lo | (hi << 16);
        }
        w2f[i] = r;
    }
    for (int i = tid; i < emb_pairs; i += 8192) {
        unsigned lo = f32_bf16_rne(emb[2 * i]);
        unsigned hi = f32_bf16_rne(emb[2 * i + 1]);
        emb16[i] = lo | (hi << 16);
    }
    if (tid == 0) {                                   // uniform temporal-LN sums
        float Sw = 0.f, Sb = 0.f, Sww = 0.f, Swb = 0.f, Sbb = 0.f;
        for (int j = 0; j < 32; ++j) {
            const float ww = tp_w[j], bb = tp_b[j];
            Sw += ww; Sb += bb; Sww += ww * ww; Swb += ww * bb; Sbb += bb * bb;
        }
        float* tps = (float*)(emb16 + emb_pairs);
        tps[0] = Sw; tps[1] = Sb; tps[2] = Sww; tps[3] = Swb; tps[4] = Sbb;
    }
}

// -------- main: one block per batch row. 4 waves loop over 16-row tiles
//          (t = w, w+4, ...): no early-exit waves, balanced, prologue amortized.
//          Pool accumulated in registers, combined via LDS -> ONE plain store
//          per row (zero atomics).
// __launch_bounds__(256,4): 128-VGPR budget. (256,5) => 102 regs => the
// compiler spilled the tile loop to scratch: 1.3 GB/dispatch HBM R/W, 2.5x
// regression (round-2 counters: FETCH 648 MB, WRITE 686 MB, VGPR_Count 48).
__global__ __launch_bounds__(256, 4) void encoder_mfma(
    const int*   __restrict__ tids,  const float* __restrict__ dates,
    const int*   __restrict__ lengths,
    const float* __restrict__ tp_w,  const float* __restrict__ tp_b,
    const float* __restrict__ tp_lnw,const float* __restrict__ tp_lnb,
    const float* __restrict__ b1,    const float* __restrict__ ln1w, const float* __restrict__ ln1b,
    const float* __restrict__ b2,    const float* __restrict__ ln2w, const float* __restrict__ ln2b,
    const unsigned* __restrict__ ws, float* __restrict__ out, int L, int emb_pairs)
{
    // per-wave C->A transpose scratch: [wave][kt2][row64 (XOR-swizzled)][j]
    __shared__ __align__(16) unsigned short a2[4][4][64][8];   // 16 KB
    __shared__ float poolbuf[4][128];                          // 2 KB

    const int b   = blockIdx.x;
    const int tid = threadIdx.x;
    const int lane = tid & 63, w = tid >> 6;
    const int c = lane & 15, g = lane >> 4;
    const int len = min(max(lengths[b], 0), L);
    const int ntiles = (len + 15) >> 4;               // 0..13

    const uint4v* w1f = (const uint4v*)ws;
    const uint4v* w2f = w1f + W1F_U4;
    const unsigned short* emb16 = (const unsigned short*)(w2f + W2F_U4);
    const float* tps = (const float*)(emb16 + emb_pairs * 2);
    const float Sw = tps[0], Sb = tps[1], Sww = tps[2], Swb = tps[3], Sbb = tps[4];

    // hoisted per-lane epilogue coefficients (col = nt*16 + c)
    float l1w[8], l1b[8], bb1[8], l2w[8], l2b[8], bb2[8], pool[8];
    #pragma unroll
    for (int nt = 0; nt < 8; ++nt) {
        const int col = nt * 16 + c;
        l1w[nt] = ln1w[col]; l1b[nt] = ln1b[col]; bb1[nt] = b1[col];
        l2w[nt] = ln2w[col]; l2b[nt] = ln2b[col]; bb2[nt] = b2[col];
        pool[nt] = 0.f;
    }
    const int srl = lane ^ ((lane >> 3) & 3);          // swizzled GEMM2 read row

    for (int t = w; t < ntiles; t += 4) {
        const int R0 = t << 4;
        const int pc = min(R0 + c, L - 1);
        const int id = tids[b * L + pc];
        const float d = dates[b * L + pc] * (1.f / 1825.f);

        // temporal A-frag (row = c, k-chunk = g*8..g*8+7)
        short8 tfrag;
        {
            const float tm = fmaf(d, Sw, Sb) * (1.f / 32.f);
            float tv = fmaf(d * d, Sww, fmaf(2.f * d, Swb, Sbb)) * (1.f / 32.f) - tm * tm;
            const float trs = rsqrtf(fmaxf(tv, 0.f) + LN_EPS);
            const int j0 = g * 8;
            uint4v r;
            #pragma unroll
            for (int j2 = 0; j2 < 4; ++j2) {
                const float w0 = tp_w[j0 + 2*j2],   bq0 = tp_b[j0 + 2*j2];
                const float w1v = tp_w[j0 + 2*j2+1], bq1 = tp_b[j0 + 2*j2+1];
                const float y0 = fmaf((fmaf(d, w0,  bq0) - tm) * trs, tp_lnw[j0 + 2*j2],   tp_lnb[j0 + 2*j2]);
                const float y1 = fmaf((fmaf(d, w1v, bq1) - tm) * trs, tp_lnw[j0 + 2*j2+1], tp_lnb[j0 + 2*j2+1]);
                r[j2] = cvt_pk_bf16(gelu_f(y0), gelu_f(y1));
            }
            union { uint4v u; short8 s; } cv; cv.u = r;
            tfrag = cv.s;
        }

        // ---------------- GEMM1: [16 x K=160] @ w1 ----------------
        f32x4 acc[8];
        #pragma unroll
        for (int nt = 0; nt < 8; ++nt) acc[nt] = (f32x4){0.f, 0.f, 0.f, 0.f};
        #pragma unroll
        for (int kt = 0; kt < 5; ++kt) {
            const short8 af = (kt < 4) ? *(const short8*)(emb16 + id * 128 + kt * 32 + g * 8)
                                       : tfrag;
            #pragma unroll
            for (int nt = 0; nt < 8; ++nt) {
                const short8 bf = ((const short8*)w1f)[(kt * 8 + nt) * 64 + lane];
                acc[nt] = __builtin_amdgcn_mfma_f32_16x16x32_bf16(af, bf, acc[nt], 0, 0, 0);
            }
        }

        // ------- epilogue 1: +b1, LN1 (DPP reduce), GELU -> bf16 a2 (swizzled) -------
        #pragma unroll
        for (int r = 0; r < 4; ++r) {
            float v[8], s = 0.f, q = 0.f;
            #pragma unroll
            for (int nt = 0; nt < 8; ++nt) {
                v[nt] = acc[nt][r] + bb1[nt];
                s += v[nt]; q = fmaf(v[nt], v[nt], q);
            }
            s = red16(s); q = red16(q);
            const float mean = s * (1.f / 128.f);
            const float var  = fmaxf(q * (1.f / 128.f) - mean * mean, 0.f);
            const float rstd = rsqrtf(var + LN_EPS);
            const int mrow = 4 * g + r;
            #pragma unroll
            for (int n2 = 0; n2 < 4; ++n2) {
                const float y0 = gelu_f(fmaf((v[2*n2]   - mean) * rstd, l1w[2*n2],   l1b[2*n2]));
                const float y1 = gelu_f(fmaf((v[2*n2+1] - mean) * rstd, l1w[2*n2+1], l1b[2*n2+1]));
                const unsigned pk = cvt_pk_bf16(y0, y1);
                {
                    const int kcol  = (2*n2) * 16 + c;
                    const int row64 = ((kcol >> 3) & 3) * 16 + mrow;
                    const int srow  = row64 ^ ((row64 >> 3) & 3);
                    a2[w][kcol >> 5][srow][kcol & 7] = (unsigned short)(pk & 0xffffu);
                }
                {
                    const int kcol  = (2*n2+1) * 16 + c;
                    const int row64 = ((kcol >> 3) & 3) * 16 + mrow;
                    const int srow  = row64 ^ ((row64 >> 3) & 3);
                    a2[w][kcol >> 5][srow][kcol & 7] = (unsigned short)(pk >> 16);
                }
            }
        }

        // wave-local LDS write->read ordering
        asm volatile("s_waitcnt lgkmcnt(0)" ::: "memory");
        __builtin_amdgcn_sched_barrier(0);

        // ---------------- GEMM2: a2 @ w2 ----------------
        f32x4 acc2[8];
        #pragma unroll
        for (int nt = 0; nt < 8; ++nt) acc2[nt] = (f32x4){0.f, 0.f, 0.f, 0.f};
        #pragma unroll
        for (int kt2 = 0; kt2 < 4; ++kt2) {
            short8 af;
            __builtin_memcpy(&af, &a2[w][kt2][srl][0], 16);
            #pragma unroll
            for (int nt = 0; nt < 8; ++nt) {
                const short8 bf = ((const short8*)w2f)[(kt2 * 8 + nt) * 64 + lane];
                acc2[nt] = __builtin_amdgcn_mfma_f32_16x16x32_bf16(af, bf, acc2[nt], 0, 0, 0);
            }
        }

        // ---------------- epilogue 2: +b2, LN2, mask, pool (registers) ----------------
        #pragma unroll
        for (int r = 0; r < 4; ++r) {
            float v[8], s = 0.f, q = 0.f;
            #pragma unroll
            for (int nt = 0; nt < 8; ++nt) {
                v[nt] = acc2[nt][r] + bb2[nt];
                s += v[nt]; q = fmaf(v[nt], v[nt], q);
            }
            s = red16(s); q = red16(q);
            const float mean = s * (1.f / 128.f);
            const float var  = fmaxf(q * (1.f / 128.f) - mean * mean, 0.f);
            const float rstd = rsqrtf(var + LN_EPS);
            const int p = R0 + 4 * g + r;
            const float msk = (p < len) ? 1.f : 0.f;
            #pragma unroll
            for (int nt = 0; nt < 8; ++nt) {
                const float y = fmaf((v[nt] - mean) * rstd, l2w[nt], l2b[nt]);
                pool[nt] = fmaf(y, msk, pool[nt]);
            }
        }
    }

    // wave-level pool reduce (over g groups), then cross-wave combine in LDS
    #pragma unroll
    for (int nt = 0; nt < 8; ++nt) {
        float tv = pool[nt];
        tv += __shfl_xor(tv, 16);
        tv += __shfl_xor(tv, 32);
        pool[nt] = tv;
    }
    if (g == 0) {
        #pragma unroll
        for (int nt = 0; nt < 8; ++nt) poolbuf[w][nt * 16 + c] = pool[nt];
    }
    __syncthreads();
    if (tid < 128) {
        const float s = poolbuf[0][tid] + poolbuf[1][tid] + poolbuf[2][tid] + poolbuf[3][tid];
        out[b * 128 + tid] = (len > 0) ? s / (float)len : 0.f;
    }
}

extern "C" void kernel_launch(void* const* d_in, const int* in_sizes, int n_in,
                              void* d_out, int out_size, void* d_ws, size_t ws_size,
                              hipStream_t stream) {
    const int*   tids    = (const int*)  d_in[0];
    const float* dates   = (const float*)d_in[1];
    const int*   lengths = (const int*)  d_in[2];
    const float* emb     = (const float*)d_in[3];
    const float* tp_w    = (const float*)d_in[4];
    const float* tp_b    = (const float*)d_in[5];
    const float* tp_lnw  = (const float*)d_in[6];
    const float* tp_lnb  = (const float*)d_in[7];
    const float* w1      = (const float*)d_in[8];
    const float* b1      = (const float*)d_in[9];
    const float* ln1w    = (const float*)d_in[10];
    const float* ln1b    = (const float*)d_in[11];
    const float* w2      = (const float*)d_in[12];
    const float* b2      = (const float*)d_in[13];
    const float* ln2w    = (const float*)d_in[14];
    const float* ln2b    = (const float*)d_in[15];
    float* out = (float*)d_out;

    const int B = in_sizes[2];
    const int L = in_sizes[0] / B;
    const int emb_pairs = in_sizes[3] / 2;

    hipLaunchKernelGGL(prep_kernel, dim3(32), dim3(256), 0, stream,
                       w1, w2, emb, tp_w, tp_b, (unsigned*)d_ws, emb_pairs);
    hipLaunchKernelGGL(encoder_mfma, dim3(B), dim3(256), 0, stream,
                       tids, dates, lengths, tp_w, tp_b, tp_lnw, tp_lnb,
                       b1, ln1w, ln1b, b2, ln2w, ln2b,
                       (const unsigned*)d_ws, out, L, emb_pairs);
}

// Round 4
// 525.234 us; speedup vs baseline: 1.1108x; 1.0410x over previous
//
#include <hip/hip_runtime.h>
#include <cmath>

#define LN_EPS 1e-5f

typedef float  f32x4  __attribute__((ext_vector_type(4)));
typedef short  short8 __attribute__((ext_vector_type(8)));
typedef unsigned int uint4v __attribute__((ext_vector_type(4)));

// ws layout (bytes):
//   w1f  : 5*8*64*16 = 40960   (uint4 frags, B-operand layout, bf16)
//   w2f  : 4*8*64*16 = 32768
//   emb16: NUM_TYPES*128*2     (row-major bf16)
//   tps  : 5 floats (uniform temporal-LN closed-form sums)
#define W1F_U4 2560   // 5*8*64
#define W2F_U4 2048   // 4*8*64

__device__ __forceinline__ unsigned short f32_bf16_rne(float f) {
    union { float f; unsigned u; } v; v.f = f;
    unsigned r = v.u + 0x7FFFu + ((v.u >> 16) & 1u);
    return (unsigned short)(r >> 16);
}

// packed f32->bf16 (RNE), 1 VALU op for 2 elements
__device__ __forceinline__ unsigned cvt_pk_bf16(float lo, float hi) {
    unsigned r;
    asm("v_cvt_pk_bf16_f32 %0, %1, %2" : "=v"(r) : "v"(lo), "v"(hi));
    return r;
}

// exact-erf GELU via Abramowitz&Stegun 7.1.26 (|err| <= 1.5e-7)
__device__ __forceinline__ float gelu_f(float x) {
    float ax = fabsf(x);
    float a  = ax * 0.70710678118654752f;          // |x|/sqrt(2)
    float t  = __builtin_amdgcn_rcpf(fmaf(0.3275911f, a, 1.0f));
    float p  = t * fmaf(t, fmaf(t, fmaf(t, fmaf(t, 1.061405429f, -1.453152027f),
                                        1.421413741f), -0.284496736f), 0.254829592f);
    float e  = __builtin_amdgcn_exp2f(-1.44269504089f * a * a);
    float E  = fmaf(-p, e, 1.0f);                  // erf(|x|/sqrt2)
    return 0.5f * fmaf(ax, E, x);                  // 0.5*(x + |x|*erf)
}

// DPP row-rotate add: sum over the 16-lane DPP row, all lanes get the result.
template<int C>
__device__ __forceinline__ float dpp_radd(float x) {
    int t = __builtin_amdgcn_update_dpp(0, __builtin_bit_cast(int, x), C, 0xF, 0xF, true);
    return x + __builtin_bit_cast(float, t);
}
__device__ __forceinline__ float red16(float x) {
    x = dpp_radd<0x128>(x);   // row_ror:8
    x = dpp_radd<0x124>(x);   // row_ror:4
    x = dpp_radd<0x122>(x);   // row_ror:2
    x = dpp_radd<0x121>(x);   // row_ror:1
    return x;
}

// -------- prep: swizzle w1/w2 into MFMA B-fragment layout (bf16), convert emb
//          to bf16 rows, compute temporal-LN sums. Re-run every call.
__global__ void prep_kernel(const float* __restrict__ w1, const float* __restrict__ w2,
                            const float* __restrict__ emb,
                            const float* __restrict__ tp_w, const float* __restrict__ tp_b,
                            unsigned* __restrict__ ws, int emb_pairs) {
    const int tid = blockIdx.x * 256 + threadIdx.x;   // 8192 threads
    uint4v* w1f = (uint4v*)ws;
    uint4v* w2f = w1f + W1F_U4;
    unsigned* emb16 = (unsigned*)(w2f + W2F_U4);

    for (int i = tid; i < W1F_U4; i += 8192) {        // frag(kt,nt,lane): B[k][n]
        const int lane = i & 63, nt = (i >> 6) & 7, kt = i >> 9;
        const int k0 = kt * 32 + (lane >> 4) * 8, n = nt * 16 + (lane & 15);
        uint4v r;
        #pragma unroll
        for (int j2 = 0; j2 < 4; ++j2) {
            unsigned lo = f32_bf16_rne(w1[(k0 + 2 * j2) * 128 + n]);
            unsigned hi = f32_bf16_rne(w1[(k0 + 2 * j2 + 1) * 128 + n]);
            r[j2] = lo | (hi << 16);
        }
        w1f[i] = r;
    }
    for (int i = tid; i < W2F_U4; i += 8192) {
        const int lane = i & 63, nt = (i >> 6) & 7, kt = i >> 9;
        const int k0 = kt * 32 + (lane >> 4) * 8, n = nt * 16 + (lane & 15);
        uint4v r;
        #pragma unroll
        for (int j2 = 0; j2 < 4; ++j2) {
            unsigned lo = f32_bf16_rne(w2[(k0 + 2 * j2) * 128 + n]);
            unsigned hi = f32_bf16_rne(w2[(k0 + 2 * j2 + 1) * 128 + n]);
            r[j2] = lo | (hi << 16);
        }
        w2f[i] = r;
    }
    for (int i = tid; i < emb_pairs; i += 8192) {
        unsigned lo = f32_bf16_rne(emb[2 * i]);
        unsigned hi = f32_bf16_rne(emb[2 * i + 1]);
        emb16[i] = lo | (hi << 16);
    }
    if (tid == 0) {                                   // uniform temporal-LN sums
        float Sw = 0.f, Sb = 0.f, Sww = 0.f, Swb = 0.f, Sbb = 0.f;
        for (int j = 0; j < 32; ++j) {
            const float ww = tp_w[j], bb = tp_b[j];
            Sw += ww; Sb += bb; Sww += ww * ww; Swb += ww * bb; Sbb += bb * bb;
        }
        float* tps = (float*)(emb16 + emb_pairs);
        tps[0] = Sw; tps[1] = Sb; tps[2] = Sww; tps[3] = Swb; tps[4] = Sbb;
    }
}

// -------- main: one block per batch row. 4 waves loop over 16-row tiles
//          (t = w, w+4, ...): no early-exit waves, balanced, prologue amortized.
//          Pool accumulated in registers, combined via LDS -> ONE plain store
//          per row (zero atomics).
//
// REGISTER BUDGET (gfx950 unified VGPR/AGPR file): with MFMA present the
// compiler splits the per-wave budget ~half arch-VGPR / half AGPR.
//   (256,5) -> 102 total ->  48 arch : spilled, 1.3 GB/dispatch HBM traffic
//   (256,4) -> 128 total ->  64 arch : spilled, 1.1 GB/dispatch
//   (256,3) -> 170 total -> ~96 arch : fits the ~90-reg live set, no spill
// Do NOT tighten below 3.
__global__ __launch_bounds__(256, 3) void encoder_mfma(
    const int*   __restrict__ tids,  const float* __restrict__ dates,
    const int*   __restrict__ lengths,
    const float* __restrict__ tp_w,  const float* __restrict__ tp_b,
    const float* __restrict__ tp_lnw,const float* __restrict__ tp_lnb,
    const float* __restrict__ b1,    const float* __restrict__ ln1w, const float* __restrict__ ln1b,
    const float* __restrict__ b2,    const float* __restrict__ ln2w, const float* __restrict__ ln2b,
    const unsigned* __restrict__ ws, float* __restrict__ out, int L, int emb_pairs)
{
    // per-wave C->A transpose scratch: [wave][kt2][row64 (XOR-swizzled)][j]
    __shared__ __align__(16) unsigned short a2[4][4][64][8];   // 16 KB
    __shared__ float poolbuf[4][128];                          // 2 KB

    const int b   = blockIdx.x;
    const int tid = threadIdx.x;
    const int lane = tid & 63, w = tid >> 6;
    const int c = lane & 15, g = lane >> 4;
    const int len = min(max(lengths[b], 0), L);
    const int ntiles = (len + 15) >> 4;               // 0..13

    const uint4v* w1f = (const uint4v*)ws;
    const uint4v* w2f = w1f + W1F_U4;
    const unsigned short* emb16 = (const unsigned short*)(w2f + W2F_U4);
    const float* tps = (const float*)(emb16 + emb_pairs * 2);
    const float Sw = tps[0], Sb = tps[1], Sww = tps[2], Swb = tps[3], Sbb = tps[4];

    // hoisted per-lane epilogue coefficients (col = nt*16 + c)
    float l1w[8], l1b[8], bb1[8], l2w[8], l2b[8], bb2[8], pool[8];
    #pragma unroll
    for (int nt = 0; nt < 8; ++nt) {
        const int col = nt * 16 + c;
        l1w[nt] = ln1w[col]; l1b[nt] = ln1b[col]; bb1[nt] = b1[col];
        l2w[nt] = ln2w[col]; l2b[nt] = ln2b[col]; bb2[nt] = b2[col];
        pool[nt] = 0.f;
    }
    const int srl = lane ^ ((lane >> 3) & 3);          // swizzled GEMM2 read row

    for (int t = w; t < ntiles; t += 4) {
        const int R0 = t << 4;
        const int pc = min(R0 + c, L - 1);
        const int id = tids[b * L + pc];
        const float d = dates[b * L + pc] * (1.f / 1825.f);

        // temporal A-frag (row = c, k-chunk = g*8..g*8+7)
        short8 tfrag;
        {
            const float tm = fmaf(d, Sw, Sb) * (1.f / 32.f);
            float tv = fmaf(d * d, Sww, fmaf(2.f * d, Swb, Sbb)) * (1.f / 32.f) - tm * tm;
            const float trs = rsqrtf(fmaxf(tv, 0.f) + LN_EPS);
            const int j0 = g * 8;
            uint4v r;
            #pragma unroll
            for (int j2 = 0; j2 < 4; ++j2) {
                const float w0 = tp_w[j0 + 2*j2],   bq0 = tp_b[j0 + 2*j2];
                const float w1v = tp_w[j0 + 2*j2+1], bq1 = tp_b[j0 + 2*j2+1];
                const float y0 = fmaf((fmaf(d, w0,  bq0) - tm) * trs, tp_lnw[j0 + 2*j2],   tp_lnb[j0 + 2*j2]);
                const float y1 = fmaf((fmaf(d, w1v, bq1) - tm) * trs, tp_lnw[j0 + 2*j2+1], tp_lnb[j0 + 2*j2+1]);
                r[j2] = cvt_pk_bf16(gelu_f(y0), gelu_f(y1));
            }
            union { uint4v u; short8 s; } cv; cv.u = r;
            tfrag = cv.s;
        }

        // ---------------- GEMM1: [16 x K=160] @ w1 ----------------
        f32x4 acc[8];
        #pragma unroll
        for (int nt = 0; nt < 8; ++nt) acc[nt] = (f32x4){0.f, 0.f, 0.f, 0.f};
        #pragma unroll
        for (int kt = 0; kt < 5; ++kt) {
            const short8 af = (kt < 4) ? *(const short8*)(emb16 + id * 128 + kt * 32 + g * 8)
                                       : tfrag;
            #pragma unroll
            for (int nt = 0; nt < 8; ++nt) {
                const short8 bf = ((const short8*)w1f)[(kt * 8 + nt) * 64 + lane];
                acc[nt] = __builtin_amdgcn_mfma_f32_16x16x32_bf16(af, bf, acc[nt], 0, 0, 0);
            }
        }

        // ------- epilogue 1: +b1, LN1 (DPP reduce), GELU -> bf16 a2 (swizzled) -------
        #pragma unroll
        for (int r = 0; r < 4; ++r) {
            float v[8], s = 0.f, q = 0.f;
            #pragma unroll
            for (int nt = 0; nt < 8; ++nt) {
                v[nt] = acc[nt][r] + bb1[nt];
                s += v[nt]; q = fmaf(v[nt], v[nt], q);
            }
            s = red16(s); q = red16(q);
            const float mean = s * (1.f / 128.f);
            const float var  = fmaxf(q * (1.f / 128.f) - mean * mean, 0.f);
            const float rstd = rsqrtf(var + LN_EPS);
            const int mrow = 4 * g + r;
            #pragma unroll
            for (int n2 = 0; n2 < 4; ++n2) {
                const float y0 = gelu_f(fmaf((v[2*n2]   - mean) * rstd, l1w[2*n2],   l1b[2*n2]));
                const float y1 = gelu_f(fmaf((v[2*n2+1] - mean) * rstd, l1w[2*n2+1], l1b[2*n2+1]));
                const unsigned pk = cvt_pk_bf16(y0, y1);
                {
                    const int kcol  = (2*n2) * 16 + c;
                    const int row64 = ((kcol >> 3) & 3) * 16 + mrow;
                    const int srow  = row64 ^ ((row64 >> 3) & 3);
                    a2[w][kcol >> 5][srow][kcol & 7] = (unsigned short)(pk & 0xffffu);
                }
                {
                    const int kcol  = (2*n2+1) * 16 + c;
                    const int row64 = ((kcol >> 3) & 3) * 16 + mrow;
                    const int srow  = row64 ^ ((row64 >> 3) & 3);
                    a2[w][kcol >> 5][srow][kcol & 7] = (unsigned short)(pk >> 16);
                }
            }
        }

        // wave-local LDS write->read ordering
        asm volatile("s_waitcnt lgkmcnt(0)" ::: "memory");
        __builtin_amdgcn_sched_barrier(0);

        // ---------------- GEMM2: a2 @ w2 ----------------
        f32x4 acc2[8];
        #pragma unroll
        for (int nt = 0; nt < 8; ++nt) acc2[nt] = (f32x4){0.f, 0.f, 0.f, 0.f};
        #pragma unroll
        for (int kt2 = 0; kt2 < 4; ++kt2) {
            short8 af;
            __builtin_memcpy(&af, &a2[w][kt2][srl][0], 16);
            #pragma unroll
            for (int nt = 0; nt < 8; ++nt) {
                const short8 bf = ((const short8*)w2f)[(kt2 * 8 + nt) * 64 + lane];
                acc2[nt] = __builtin_amdgcn_mfma_f32_16x16x32_bf16(af, bf, acc2[nt], 0, 0, 0);
            }
        }

        // ---------------- epilogue 2: +b2, LN2, mask, pool (registers) ----------------
        #pragma unroll
        for (int r = 0; r < 4; ++r) {
            float v[8], s = 0.f, q = 0.f;
            #pragma unroll
            for (int nt = 0; nt < 8; ++nt) {
                v[nt] = acc2[nt][r] + bb2[nt];
                s += v[nt]; q = fmaf(v[nt], v[nt], q);
            }
            s = red16(s); q = red16(q);
            const float mean = s * (1.f / 128.f);
            const float var  = fmaxf(q * (1.f / 128.f) - mean * mean, 0.f);
            const float rstd = rsqrtf(var + LN_EPS);
            const int p = R0 + 4 * g + r;
            const float msk = (p < len) ? 1.f : 0.f;
            #pragma unroll
            for (int nt = 0; nt < 8; ++nt) {
                const float y = fmaf((v[nt] - mean) * rstd, l2w[nt], l2b[nt]);
                pool[nt] = fmaf(y, msk, pool[nt]);
            }
        }
    }

    // wave-level pool reduce (over g groups), then cross-wave combine in LDS
    #pragma unroll
    for (int nt = 0; nt < 8; ++nt) {
        float tv = pool[nt];
        tv += __shfl_xor(tv, 16);
        tv += __shfl_xor(tv, 32);
        pool[nt] = tv;
    }
    if (g == 0) {
        #pragma unroll
        for (int nt = 0; nt < 8; ++nt) poolbuf[w][nt * 16 + c] = pool[nt];
    }
    __syncthreads();
    if (tid < 128) {
        const float s = poolbuf[0][tid] + poolbuf[1][tid] + poolbuf[2][tid] + poolbuf[3][tid];
        out[b * 128 + tid] = (len > 0) ? s / (float)len : 0.f;
    }
}

extern "C" void kernel_launch(void* const* d_in, const int* in_sizes, int n_in,
                              void* d_out, int out_size, void* d_ws, size_t ws_size,
                              hipStream_t stream) {
    const int*   tids    = (const int*)  d_in[0];
    const float* dates   = (const float*)d_in[1];
    const int*   lengths = (const int*)  d_in[2];
    const float* emb     = (const float*)d_in[3];
    const float* tp_w    = (const float*)d_in[4];
    const float* tp_b    = (const float*)d_in[5];
    const float* tp_lnw  = (const float*)d_in[6];
    const float* tp_lnb  = (const float*)d_in[7];
    const float* w1      = (const float*)d_in[8];
    const float* b1      = (const float*)d_in[9];
    const float* ln1w    = (const float*)d_in[10];
    const float* ln1b    = (const float*)d_in[11];
    const float* w2      = (const float*)d_in[12];
    const float* b2      = (const float*)d_in[13];
    const float* ln2w    = (const float*)d_in[14];
    const float* ln2b    = (const float*)d_in[15];
    float* out = (float*)d_out;

    const int B = in_sizes[2];
    const int L = in_sizes[0] / B;
    const int emb_pairs = in_sizes[3] / 2;

    hipLaunchKernelGGL(prep_kernel, dim3(32), dim3(256), 0, stream,
                       w1, w2, emb, tp_w, tp_b, (unsigned*)d_ws, emb_pairs);
    hipLaunchKernelGGL(encoder_mfma, dim3(B), dim3(256), 0, stream,
                       tids, dates, lengths, tp_w, tp_b, tp_lnw, tp_lnb,
                       b1, ln1w, ln1b, b2, ln2w, ln2b,
                       (const unsigned*)d_ws, out, L, emb_pairs);
}

// Round 5
// 443.219 us; speedup vs baseline: 1.3163x; 1.1850x over previous
//
#include <hip/hip_runtime.h>
#include <cmath>

#define LN_EPS 1e-5f

typedef float  f32x4  __attribute__((ext_vector_type(4)));
typedef short  short8 __attribute__((ext_vector_type(8)));
typedef unsigned int uint4v __attribute__((ext_vector_type(4)));

// ws layout (bytes):
//   w1f  : 5*8*64*16 = 40960   (uint4 frags, B-operand layout, bf16)
//   w2f  : 4*8*64*16 = 32768
//   emb16: NUM_TYPES*128*2     (row-major bf16)
//   tps  : 5 floats (uniform temporal-LN closed-form sums)
#define W1F_U4 2560   // 5*8*64
#define W2F_U4 2048   // 4*8*64

__device__ __forceinline__ unsigned short f32_bf16_rne(float f) {
    union { float f; unsigned u; } v; v.f = f;
    unsigned r = v.u + 0x7FFFu + ((v.u >> 16) & 1u);
    return (unsigned short)(r >> 16);
}

// packed f32->bf16 (RNE), 1 VALU op for 2 elements
__device__ __forceinline__ unsigned cvt_pk_bf16(float lo, float hi) {
    unsigned r;
    asm("v_cvt_pk_bf16_f32 %0, %1, %2" : "=v"(r) : "v"(lo), "v"(hi));
    return r;
}

// exact-erf GELU via Abramowitz&Stegun 7.1.26 (|err| <= 1.5e-7)
__device__ __forceinline__ float gelu_f(float x) {
    float ax = fabsf(x);
    float a  = ax * 0.70710678118654752f;          // |x|/sqrt(2)
    float t  = __builtin_amdgcn_rcpf(fmaf(0.3275911f, a, 1.0f));
    float p  = t * fmaf(t, fmaf(t, fmaf(t, fmaf(t, 1.061405429f, -1.453152027f),
                                        1.421413741f), -0.284496736f), 0.254829592f);
    float e  = __builtin_amdgcn_exp2f(-1.44269504089f * a * a);
    float E  = fmaf(-p, e, 1.0f);                  // erf(|x|/sqrt2)
    return 0.5f * fmaf(ax, E, x);                  // 0.5*(x + |x|*erf)
}

// DPP row-rotate add: sum over the 16-lane DPP row, all lanes get the result.
template<int C>
__device__ __forceinline__ float dpp_radd(float x) {
    int t = __builtin_amdgcn_update_dpp(0, __builtin_bit_cast(int, x), C, 0xF, 0xF, true);
    return x + __builtin_bit_cast(float, t);
}
__device__ __forceinline__ float red16(float x) {
    x = dpp_radd<0x128>(x);   // row_ror:8
    x = dpp_radd<0x124>(x);   // row_ror:4
    x = dpp_radd<0x122>(x);   // row_ror:2
    x = dpp_radd<0x121>(x);   // row_ror:1
    return x;
}

// -------- prep: swizzle w1/w2 into MFMA B-fragment layout (bf16), convert emb
//          to bf16 rows, compute temporal-LN sums. Re-run every call.
__global__ void prep_kernel(const float* __restrict__ w1, const float* __restrict__ w2,
                            const float* __restrict__ emb,
                            const float* __restrict__ tp_w, const float* __restrict__ tp_b,
                            unsigned* __restrict__ ws, int emb_pairs) {
    const int tid = blockIdx.x * 256 + threadIdx.x;   // 8192 threads
    uint4v* w1f = (uint4v*)ws;
    uint4v* w2f = w1f + W1F_U4;
    unsigned* emb16 = (unsigned*)(w2f + W2F_U4);

    for (int i = tid; i < W1F_U4; i += 8192) {        // frag(kt,nt,lane): B[k][n]
        const int lane = i & 63, nt = (i >> 6) & 7, kt = i >> 9;
        const int k0 = kt * 32 + (lane >> 4) * 8, n = nt * 16 + (lane & 15);
        uint4v r;
        #pragma unroll
        for (int j2 = 0; j2 < 4; ++j2) {
            unsigned lo = f32_bf16_rne(w1[(k0 + 2 * j2) * 128 + n]);
            unsigned hi = f32_bf16_rne(w1[(k0 + 2 * j2 + 1) * 128 + n]);
            r[j2] = lo | (hi << 16);
        }
        w1f[i] = r;
    }
    for (int i = tid; i < W2F_U4; i += 8192) {
        const int lane = i & 63, nt = (i >> 6) & 7, kt = i >> 9;
        const int k0 = kt * 32 + (lane >> 4) * 8, n = nt * 16 + (lane & 15);
        uint4v r;
        #pragma unroll
        for (int j2 = 0; j2 < 4; ++j2) {
            unsigned lo = f32_bf16_rne(w2[(k0 + 2 * j2) * 128 + n]);
            unsigned hi = f32_bf16_rne(w2[(k0 + 2 * j2 + 1) * 128 + n]);
            r[j2] = lo | (hi << 16);
        }
        w2f[i] = r;
    }
    for (int i = tid; i < emb_pairs; i += 8192) {
        unsigned lo = f32_bf16_rne(emb[2 * i]);
        unsigned hi = f32_bf16_rne(emb[2 * i + 1]);
        emb16[i] = lo | (hi << 16);
    }
    if (tid == 0) {                                   // uniform temporal-LN sums
        float Sw = 0.f, Sb = 0.f, Sww = 0.f, Swb = 0.f, Sbb = 0.f;
        for (int j = 0; j < 32; ++j) {
            const float ww = tp_w[j], bb = tp_b[j];
            Sw += ww; Sb += bb; Sww += ww * ww; Swb += ww * bb; Sbb += bb * bb;
        }
        float* tps = (float*)(emb16 + emb_pairs);
        tps[0] = Sw; tps[1] = Sb; tps[2] = Sww; tps[3] = Swb; tps[4] = Sbb;
    }
}

// -------- main: one block per batch row. 4 waves loop over 16-row tiles
//          (t = w, w+4, ...): balanced, no early-exit waves. Pool in registers,
//          cross-wave combine in LDS -> ONE plain store per row (zero atomics).
//
// REGISTER DISCIPLINE (the round-2..4 spill saga): the per-tile loop must NOT
// keep large loop-invariant arrays in registers. At (256,3) the arch-VGPR side
// of the unified file is 84 regs; the 56-reg hoisted coefficient set pushed the
// peak to ~110 -> per-iteration scratch spills (780 MB/dispatch HBM, entire
// runtime). Fix: coefficients live in LDS (tcoef/ecoef1/ecoef2), re-read per
// tile as ds_read_b128; register live range = one epilogue only.
__global__ __launch_bounds__(256, 3) void encoder_mfma(
    const int*   __restrict__ tids,  const float* __restrict__ dates,
    const int*   __restrict__ lengths,
    const float* __restrict__ tp_w,  const float* __restrict__ tp_b,
    const float* __restrict__ tp_lnw,const float* __restrict__ tp_lnb,
    const float* __restrict__ b1,    const float* __restrict__ ln1w, const float* __restrict__ ln1b,
    const float* __restrict__ b2,    const float* __restrict__ ln2w, const float* __restrict__ ln2b,
    const unsigned* __restrict__ ws, float* __restrict__ out, int L, int emb_pairs)
{
    // per-wave C->A transpose scratch: [wave][kt2][row64 (XOR-swizzled)][j]
    __shared__ __align__(16) unsigned short a2[4][4][64][8];   // 16 KB
    __shared__ float poolbuf[4][128];                          // 2 KB
    // loop-invariant coefficients, packed f32x4 per column (16B stride ->
    // worst-case 2-way bank aliasing = free):
    __shared__ __align__(16) f32x4 tcoef[32];    // {tp_w, tp_b, tp_lnw, tp_lnb}
    __shared__ __align__(16) f32x4 ecoef1[128];  // {b1, ln1w, ln1b, -}
    __shared__ __align__(16) f32x4 ecoef2[128];  // {b2, ln2w, ln2b, -}

    const int b   = blockIdx.x;
    const int tid = threadIdx.x;
    const int lane = tid & 63, w = tid >> 6;
    const int c = lane & 15, g = lane >> 4;
    const int len = min(max(lengths[b], 0), L);
    const int ntiles = (len + 15) >> 4;               // 0..13

    const uint4v* w1f = (const uint4v*)ws;
    const uint4v* w2f = w1f + W1F_U4;
    const unsigned short* emb16 = (const unsigned short*)(w2f + W2F_U4);
    const float* tps = (const float*)(emb16 + emb_pairs * 2);

    // fill coefficient LDS (block prologue, one barrier)
    if (tid < 32)  tcoef[tid]  = (f32x4){tp_w[tid], tp_b[tid], tp_lnw[tid], tp_lnb[tid]};
    if (tid < 128) {
        ecoef1[tid] = (f32x4){b1[tid], ln1w[tid], ln1b[tid], 0.f};
        ecoef2[tid] = (f32x4){b2[tid], ln2w[tid], ln2b[tid], 0.f};
    }
    __syncthreads();

    const float Sw = tps[0], Sb = tps[1], Sww = tps[2], Swb = tps[3], Sbb = tps[4];

    float pool[8];
    #pragma unroll
    for (int nt = 0; nt < 8; ++nt) pool[nt] = 0.f;
    const int srl = lane ^ ((lane >> 3) & 3);          // swizzled GEMM2 read row

    for (int t = w; t < ntiles; t += 4) {
        const int R0 = t << 4;
        const int pc = min(R0 + c, L - 1);
        const int id = tids[b * L + pc];
        const float d = dates[b * L + pc] * (1.f / 1825.f);

        // temporal A-frag (row = c, k-chunk = g*8..g*8+7); coeffs from LDS
        short8 tfrag;
        {
            const float tm = fmaf(d, Sw, Sb) * (1.f / 32.f);
            float tv = fmaf(d * d, Sww, fmaf(2.f * d, Swb, Sbb)) * (1.f / 32.f) - tm * tm;
            const float trs = rsqrtf(fmaxf(tv, 0.f) + LN_EPS);
            const int j0 = g * 8;
            uint4v r;
            #pragma unroll
            for (int j2 = 0; j2 < 4; ++j2) {
                const f32x4 t0 = tcoef[j0 + 2*j2];
                const f32x4 t1 = tcoef[j0 + 2*j2 + 1];
                const float y0 = fmaf((fmaf(d, t0[0], t0[1]) - tm) * trs, t0[2], t0[3]);
                const float y1 = fmaf((fmaf(d, t1[0], t1[1]) - tm) * trs, t1[2], t1[3]);
                r[j2] = cvt_pk_bf16(gelu_f(y0), gelu_f(y1));
            }
            union { uint4v u; short8 s; } cv; cv.u = r;
            tfrag = cv.s;
        }

        // ---------------- GEMM1: [16 x K=160] @ w1 ----------------
        f32x4 acc[8];
        #pragma unroll
        for (int nt = 0; nt < 8; ++nt) acc[nt] = (f32x4){0.f, 0.f, 0.f, 0.f};
        #pragma unroll
        for (int kt = 0; kt < 5; ++kt) {
            const short8 af = (kt < 4) ? *(const short8*)(emb16 + id * 128 + kt * 32 + g * 8)
                                       : tfrag;
            #pragma unroll
            for (int nt = 0; nt < 8; ++nt) {
                const short8 bf = ((const short8*)w1f)[(kt * 8 + nt) * 64 + lane];
                acc[nt] = __builtin_amdgcn_mfma_f32_16x16x32_bf16(af, bf, acc[nt], 0, 0, 0);
            }
        }

        // ------- epilogue 1: +b1, LN1 (DPP reduce), GELU -> bf16 a2 (swizzled) -------
        {
            f32x4 e1[8];
            #pragma unroll
            for (int nt = 0; nt < 8; ++nt) e1[nt] = ecoef1[nt * 16 + c];
            #pragma unroll
            for (int r = 0; r < 4; ++r) {
                float v[8], s = 0.f, q = 0.f;
                #pragma unroll
                for (int nt = 0; nt < 8; ++nt) {
                    v[nt] = acc[nt][r] + e1[nt][0];
                    s += v[nt]; q = fmaf(v[nt], v[nt], q);
                }
                s = red16(s); q = red16(q);
                const float mean = s * (1.f / 128.f);
                const float var  = fmaxf(q * (1.f / 128.f) - mean * mean, 0.f);
                const float rstd = rsqrtf(var + LN_EPS);
                const int mrow = 4 * g + r;
                #pragma unroll
                for (int n2 = 0; n2 < 4; ++n2) {
                    const float y0 = gelu_f(fmaf((v[2*n2]   - mean) * rstd, e1[2*n2][1],   e1[2*n2][2]));
                    const float y1 = gelu_f(fmaf((v[2*n2+1] - mean) * rstd, e1[2*n2+1][1], e1[2*n2+1][2]));
                    const unsigned pk = cvt_pk_bf16(y0, y1);
                    {
                        const int kcol  = (2*n2) * 16 + c;
                        const int row64 = ((kcol >> 3) & 3) * 16 + mrow;
                        const int srow  = row64 ^ ((row64 >> 3) & 3);
                        a2[w][kcol >> 5][srow][kcol & 7] = (unsigned short)(pk & 0xffffu);
                    }
                    {
                        const int kcol  = (2*n2+1) * 16 + c;
                        const int row64 = ((kcol >> 3) & 3) * 16 + mrow;
                        const int srow  = row64 ^ ((row64 >> 3) & 3);
                        a2[w][kcol >> 5][srow][kcol & 7] = (unsigned short)(pk >> 16);
                    }
                }
            }
        }

        // wave-local LDS write->read ordering
        asm volatile("s_waitcnt lgkmcnt(0)" ::: "memory");
        __builtin_amdgcn_sched_barrier(0);

        // ---------------- GEMM2: a2 @ w2 ----------------
        f32x4 acc2[8];
        #pragma unroll
        for (int nt = 0; nt < 8; ++nt) acc2[nt] = (f32x4){0.f, 0.f, 0.f, 0.f};
        #pragma unroll
        for (int kt2 = 0; kt2 < 4; ++kt2) {
            short8 af;
            __builtin_memcpy(&af, &a2[w][kt2][srl][0], 16);
            #pragma unroll
            for (int nt = 0; nt < 8; ++nt) {
                const short8 bf = ((const short8*)w2f)[(kt2 * 8 + nt) * 64 + lane];
                acc2[nt] = __builtin_amdgcn_mfma_f32_16x16x32_bf16(af, bf, acc2[nt], 0, 0, 0);
            }
        }

        // ---------------- epilogue 2: +b2, LN2, mask, pool (registers) ----------------
        {
            f32x4 e2[8];
            #pragma unroll
            for (int nt = 0; nt < 8; ++nt) e2[nt] = ecoef2[nt * 16 + c];
            #pragma unroll
            for (int r = 0; r < 4; ++r) {
                float v[8], s = 0.f, q = 0.f;
                #pragma unroll
                for (int nt = 0; nt < 8; ++nt) {
                    v[nt] = acc2[nt][r] + e2[nt][0];
                    s += v[nt]; q = fmaf(v[nt], v[nt], q);
                }
                s = red16(s); q = red16(q);
                const float mean = s * (1.f / 128.f);
                const float var  = fmaxf(q * (1.f / 128.f) - mean * mean, 0.f);
                const float rstd = rsqrtf(var + LN_EPS);
                const int p = R0 + 4 * g + r;
                const float msk = (p < len) ? 1.f : 0.f;
                #pragma unroll
                for (int nt = 0; nt < 8; ++nt) {
                    const float y = fmaf((v[nt] - mean) * rstd, e2[nt][1], e2[nt][2]);
                    pool[nt] = fmaf(y, msk, pool[nt]);
                }
            }
        }
    }

    // wave-level pool reduce (over g groups), then cross-wave combine in LDS
    #pragma unroll
    for (int nt = 0; nt < 8; ++nt) {
        float tv = pool[nt];
        tv += __shfl_xor(tv, 16);
        tv += __shfl_xor(tv, 32);
        pool[nt] = tv;
    }
    if (g == 0) {
        #pragma unroll
        for (int nt = 0; nt < 8; ++nt) poolbuf[w][nt * 16 + c] = pool[nt];
    }
    __syncthreads();
    if (tid < 128) {
        const float s = poolbuf[0][tid] + poolbuf[1][tid] + poolbuf[2][tid] + poolbuf[3][tid];
        out[b * 128 + tid] = (len > 0) ? s / (float)len : 0.f;
    }
}

extern "C" void kernel_launch(void* const* d_in, const int* in_sizes, int n_in,
                              void* d_out, int out_size, void* d_ws, size_t ws_size,
                              hipStream_t stream) {
    const int*   tids    = (const int*)  d_in[0];
    const float* dates   = (const float*)d_in[1];
    const int*   lengths = (const int*)  d_in[2];
    const float* emb     = (const float*)d_in[3];
    const float* tp_w    = (const float*)d_in[4];
    const float* tp_b    = (const float*)d_in[5];
    const float* tp_lnw  = (const float*)d_in[6];
    const float* tp_lnb  = (const float*)d_in[7];
    const float* w1      = (const float*)d_in[8];
    const float* b1      = (const float*)d_in[9];
    const float* ln1w    = (const float*)d_in[10];
    const float* ln1b    = (const float*)d_in[11];
    const float* w2      = (const float*)d_in[12];
    const float* b2      = (const float*)d_in[13];
    const float* ln2w    = (const float*)d_in[14];
    const float* ln2b    = (const float*)d_in[15];
    float* out = (float*)d_out;

    const int B = in_sizes[2];
    const int L = in_sizes[0] / B;
    const int emb_pairs = in_sizes[3] / 2;

    hipLaunchKernelGGL(prep_kernel, dim3(32), dim3(256), 0, stream,
                       w1, w2, emb, tp_w, tp_b, (unsigned*)d_ws, emb_pairs);
    hipLaunchKernelGGL(encoder_mfma, dim3(B), dim3(256), 0, stream,
                       tids, dates, lengths, tp_w, tp_b, tp_lnw, tp_lnb,
                       b1, ln1w, ln1b, b2, ln2w, ln2b,
                       (const unsigned*)d_ws, out, L, emb_pairs);
}

// Round 6
// 291.904 us; speedup vs baseline: 1.9986x; 1.5184x over previous
//
#include <hip/hip_runtime.h>
#include <cmath>

#define LN_EPS 1e-5f

typedef float  f32x4  __attribute__((ext_vector_type(4)));
typedef short  short8 __attribute__((ext_vector_type(8)));
typedef unsigned int uint4v __attribute__((ext_vector_type(4)));

// ws layout (bytes):
//   w1f  : 5*8*64*16 = 40960   (uint4 frags, B-operand layout, bf16)
//   w2f  : 4*8*64*16 = 32768
//   emb16: NUM_TYPES*128*2     (row-major bf16)
//   tps  : 5 floats (uniform temporal-LN closed-form sums)
#define W1F_U4 2560   // 5*8*64
#define W2F_U4 2048   // 4*8*64

__device__ __forceinline__ unsigned short f32_bf16_rne(float f) {
    union { float f; unsigned u; } v; v.f = f;
    unsigned r = v.u + 0x7FFFu + ((v.u >> 16) & 1u);
    return (unsigned short)(r >> 16);
}

// packed f32->bf16 (RNE), 1 VALU op for 2 elements
__device__ __forceinline__ unsigned cvt_pk_bf16(float lo, float hi) {
    unsigned r;
    asm("v_cvt_pk_bf16_f32 %0, %1, %2" : "=v"(r) : "v"(lo), "v"(hi));
    return r;
}

// exact-erf GELU via Abramowitz&Stegun 7.1.26 (|err| <= 1.5e-7)
__device__ __forceinline__ float gelu_f(float x) {
    float ax = fabsf(x);
    float a  = ax * 0.70710678118654752f;          // |x|/sqrt(2)
    float t  = __builtin_amdgcn_rcpf(fmaf(0.3275911f, a, 1.0f));
    float p  = t * fmaf(t, fmaf(t, fmaf(t, fmaf(t, 1.061405429f, -1.453152027f),
                                        1.421413741f), -0.284496736f), 0.254829592f);
    float e  = __builtin_amdgcn_exp2f(-1.44269504089f * a * a);
    float E  = fmaf(-p, e, 1.0f);                  // erf(|x|/sqrt2)
    return 0.5f * fmaf(ax, E, x);                  // 0.5*(x + |x|*erf)
}

// DPP row-rotate add: sum over the 16-lane DPP row, all lanes get the result.
template<int C>
__device__ __forceinline__ float dpp_radd(float x) {
    int t = __builtin_amdgcn_update_dpp(0, __builtin_bit_cast(int, x), C, 0xF, 0xF, true);
    return x + __builtin_bit_cast(float, t);
}
__device__ __forceinline__ float red16(float x) {
    x = dpp_radd<0x128>(x);   // row_ror:8
    x = dpp_radd<0x124>(x);   // row_ror:4
    x = dpp_radd<0x122>(x);   // row_ror:2
    x = dpp_radd<0x121>(x);   // row_ror:1
    return x;
}

// -------- prep: swizzle w1/w2 into MFMA B-fragment layout (bf16), convert emb
//          to bf16 rows, compute temporal-LN sums. Re-run every call.
__global__ void prep_kernel(const float* __restrict__ w1, const float* __restrict__ w2,
                            const float* __restrict__ emb,
                            const float* __restrict__ tp_w, const float* __restrict__ tp_b,
                            unsigned* __restrict__ ws, int emb_pairs) {
    const int tid = blockIdx.x * 256 + threadIdx.x;   // 8192 threads
    uint4v* w1f = (uint4v*)ws;
    uint4v* w2f = w1f + W1F_U4;
    unsigned* emb16 = (unsigned*)(w2f + W2F_U4);

    for (int i = tid; i < W1F_U4; i += 8192) {        // frag(kt,nt,lane): B[k][n]
        const int lane = i & 63, nt = (i >> 6) & 7, kt = i >> 9;
        const int k0 = kt * 32 + (lane >> 4) * 8, n = nt * 16 + (lane & 15);
        uint4v r;
        #pragma unroll
        for (int j2 = 0; j2 < 4; ++j2) {
            unsigned lo = f32_bf16_rne(w1[(k0 + 2 * j2) * 128 + n]);
            unsigned hi = f32_bf16_rne(w1[(k0 + 2 * j2 + 1) * 128 + n]);
            r[j2] = lo | (hi << 16);
        }
        w1f[i] = r;
    }
    for (int i = tid; i < W2F_U4; i += 8192) {
        const int lane = i & 63, nt = (i >> 6) & 7, kt = i >> 9;
        const int k0 = kt * 32 + (lane >> 4) * 8, n = nt * 16 + (lane & 15);
        uint4v r;
        #pragma unroll
        for (int j2 = 0; j2 < 4; ++j2) {
            unsigned lo = f32_bf16_rne(w2[(k0 + 2 * j2) * 128 + n]);
            unsigned hi = f32_bf16_rne(w2[(k0 + 2 * j2 + 1) * 128 + n]);
            r[j2] = lo | (hi << 16);
        }
        w2f[i] = r;
    }
    for (int i = tid; i < emb_pairs; i += 8192) {
        unsigned lo = f32_bf16_rne(emb[2 * i]);
        unsigned hi = f32_bf16_rne(emb[2 * i + 1]);
        emb16[i] = lo | (hi << 16);
    }
    if (tid == 0) {                                   // uniform temporal-LN sums
        float Sw = 0.f, Sb = 0.f, Sww = 0.f, Swb = 0.f, Sbb = 0.f;
        for (int j = 0; j < 32; ++j) {
            const float ww = tp_w[j], bb = tp_b[j];
            Sw += ww; Sb += bb; Sww += ww * ww; Swb += ww * bb; Sbb += bb * bb;
        }
        float* tps = (float*)(emb16 + emb_pairs);
        tps[0] = Sw; tps[1] = Sb; tps[2] = Sww; tps[3] = Swb; tps[4] = Sbb;
    }
}

// -------- main: one block per batch row. 4 waves loop over 32-row SUPER-tiles
//          (mt=2 x 16 rows): st = w, w+4, ... Balanced, no early-exit waves.
//          Pool in registers, cross-wave combine in LDS -> ONE plain store per
//          row (zero atomics). Weight-frag loads shared across mt (halves L2
//          weight traffic vs mt=1).
//
// REGISTER DISCIPLINE (rounds 2-5 spill saga): at (256,3) the arch-VGPR half
// of the unified file is 84 regs and this loop spills ~540 MB/dispatch to
// scratch -> entire runtime is HBM spill traffic. (256,2) = 128 arch + 128
// acc: round-0 ran mt=4 in exactly this regime with ZERO spill, and measured
// occupancy at (256,3) was 27.5% ~= the (256,2) static cap anyway.
// Do NOT tighten launch bounds below 2. Coefficients stay in LDS
// (tcoef/ecoef1/ecoef2) so their live range is one epilogue, not the loop.
__global__ __launch_bounds__(256, 2) void encoder_mfma(
    const int*   __restrict__ tids,  const float* __restrict__ dates,
    const int*   __restrict__ lengths,
    const float* __restrict__ tp_w,  const float* __restrict__ tp_b,
    const float* __restrict__ tp_lnw,const float* __restrict__ tp_lnb,
    const float* __restrict__ b1,    const float* __restrict__ ln1w, const float* __restrict__ ln1b,
    const float* __restrict__ b2,    const float* __restrict__ ln2w, const float* __restrict__ ln2b,
    const unsigned* __restrict__ ws, float* __restrict__ out, int L, int emb_pairs)
{
    // per-wave C->A transpose scratch: [wave][mt][kt2][row64 (XOR-swizzled)][j]
    __shared__ __align__(16) unsigned short a2[4][2][4][64][8];   // 32 KB
    __shared__ float poolbuf[4][128];                             // 2 KB
    // loop-invariant coefficients, packed f32x4 per column (16B stride ->
    // worst-case 2-way bank aliasing = free):
    __shared__ __align__(16) f32x4 tcoef[32];    // {tp_w, tp_b, tp_lnw, tp_lnb}
    __shared__ __align__(16) f32x4 ecoef1[128];  // {b1, ln1w, ln1b, -}
    __shared__ __align__(16) f32x4 ecoef2[128];  // {b2, ln2w, ln2b, -}

    const int b   = blockIdx.x;
    const int tid = threadIdx.x;
    const int lane = tid & 63, w = tid >> 6;
    const int c = lane & 15, g = lane >> 4;
    const int len = min(max(lengths[b], 0), L);
    const int nst = (len + 31) >> 5;                  // 32-row super-tiles

    const uint4v* w1f = (const uint4v*)ws;
    const uint4v* w2f = w1f + W1F_U4;
    const unsigned short* emb16 = (const unsigned short*)(w2f + W2F_U4);
    const float* tps = (const float*)(emb16 + emb_pairs * 2);

    // fill coefficient LDS (block prologue, one barrier)
    if (tid < 32)  tcoef[tid]  = (f32x4){tp_w[tid], tp_b[tid], tp_lnw[tid], tp_lnb[tid]};
    if (tid < 128) {
        ecoef1[tid] = (f32x4){b1[tid], ln1w[tid], ln1b[tid], 0.f};
        ecoef2[tid] = (f32x4){b2[tid], ln2w[tid], ln2b[tid], 0.f};
    }
    __syncthreads();

    const float Sw = tps[0], Sb = tps[1], Sww = tps[2], Swb = tps[3], Sbb = tps[4];

    float pool[8];
    #pragma unroll
    for (int nt = 0; nt < 8; ++nt) pool[nt] = 0.f;
    const int srl = lane ^ ((lane >> 3) & 3);          // swizzled GEMM2 read row

    for (int st = w; st < nst; st += 4) {
        const int R0 = st << 5;
        int   id[2]; float dn[2]; bool amt[2];
        #pragma unroll
        for (int mt = 0; mt < 2; ++mt) {
            const int p  = R0 + mt * 16 + c;
            const int pc = min(p, L - 1);
            id[mt]  = tids[b * L + pc];
            dn[mt]  = dates[b * L + pc] * (1.f / 1825.f);
            amt[mt] = (R0 + mt * 16) < len;            // wave-uniform
        }

        // temporal A-frags (row = c, k-chunk = g*8..g*8+7); coeffs from LDS
        short8 tfrag[2];
        #pragma unroll
        for (int mt = 0; mt < 2; ++mt) {
            const float d  = dn[mt];
            const float tm = fmaf(d, Sw, Sb) * (1.f / 32.f);
            float tv = fmaf(d * d, Sww, fmaf(2.f * d, Swb, Sbb)) * (1.f / 32.f) - tm * tm;
            const float trs = rsqrtf(fmaxf(tv, 0.f) + LN_EPS);
            const int j0 = g * 8;
            uint4v r;
            #pragma unroll
            for (int j2 = 0; j2 < 4; ++j2) {
                const f32x4 t0 = tcoef[j0 + 2*j2];
                const f32x4 t1 = tcoef[j0 + 2*j2 + 1];
                const float y0 = fmaf((fmaf(d, t0[0], t0[1]) - tm) * trs, t0[2], t0[3]);
                const float y1 = fmaf((fmaf(d, t1[0], t1[1]) - tm) * trs, t1[2], t1[3]);
                r[j2] = cvt_pk_bf16(gelu_f(y0), gelu_f(y1));
            }
            union { uint4v u; short8 s; } cv; cv.u = r;
            tfrag[mt] = cv.s;
        }

        // ---------------- GEMM1: [2mt x 16][K=160] @ w1 ----------------
        f32x4 acc[2][8];
        #pragma unroll
        for (int mt = 0; mt < 2; ++mt)
            #pragma unroll
            for (int nt = 0; nt < 8; ++nt) acc[mt][nt] = (f32x4){0.f, 0.f, 0.f, 0.f};
        #pragma unroll
        for (int kt = 0; kt < 5; ++kt) {
            short8 af[2];
            if (kt < 4) {
                #pragma unroll
                for (int mt = 0; mt < 2; ++mt)
                    af[mt] = *(const short8*)(emb16 + id[mt] * 128 + kt * 32 + g * 8);
            } else {
                #pragma unroll
                for (int mt = 0; mt < 2; ++mt) af[mt] = tfrag[mt];
            }
            #pragma unroll
            for (int nt = 0; nt < 8; ++nt) {
                const short8 bf = ((const short8*)w1f)[(kt * 8 + nt) * 64 + lane];
                #pragma unroll
                for (int mt = 0; mt < 2; ++mt)
                    acc[mt][nt] = __builtin_amdgcn_mfma_f32_16x16x32_bf16(af[mt], bf, acc[mt][nt], 0, 0, 0);
            }
        }

        // ------- epilogue 1: +b1, LN1 (DPP reduce), GELU -> bf16 a2 (swizzled) -------
        {
            f32x4 e1[8];
            #pragma unroll
            for (int nt = 0; nt < 8; ++nt) e1[nt] = ecoef1[nt * 16 + c];
            #pragma unroll
            for (int mt = 0; mt < 2; ++mt) {
                if (!amt[mt]) continue;                // wave-uniform skip
                #pragma unroll
                for (int r = 0; r < 4; ++r) {
                    float v[8], s = 0.f, q = 0.f;
                    #pragma unroll
                    for (int nt = 0; nt < 8; ++nt) {
                        v[nt] = acc[mt][nt][r] + e1[nt][0];
                        s += v[nt]; q = fmaf(v[nt], v[nt], q);
                    }
                    s = red16(s); q = red16(q);
                    const float mean = s * (1.f / 128.f);
                    const float var  = fmaxf(q * (1.f / 128.f) - mean * mean, 0.f);
                    const float rstd = rsqrtf(var + LN_EPS);
                    const int mrow = 4 * g + r;
                    #pragma unroll
                    for (int n2 = 0; n2 < 4; ++n2) {
                        const float y0 = gelu_f(fmaf((v[2*n2]   - mean) * rstd, e1[2*n2][1],   e1[2*n2][2]));
                        const float y1 = gelu_f(fmaf((v[2*n2+1] - mean) * rstd, e1[2*n2+1][1], e1[2*n2+1][2]));
                        const unsigned pk = cvt_pk_bf16(y0, y1);
                        {
                            const int kcol  = (2*n2) * 16 + c;
                            const int row64 = ((kcol >> 3) & 3) * 16 + mrow;
                            const int srow  = row64 ^ ((row64 >> 3) & 3);
                            a2[w][mt][kcol >> 5][srow][kcol & 7] = (unsigned short)(pk & 0xffffu);
                        }
                        {
                            const int kcol  = (2*n2+1) * 16 + c;
                            const int row64 = ((kcol >> 3) & 3) * 16 + mrow;
                            const int srow  = row64 ^ ((row64 >> 3) & 3);
                            a2[w][mt][kcol >> 5][srow][kcol & 7] = (unsigned short)(pk >> 16);
                        }
                    }
                }
            }
        }

        // wave-local LDS write->read ordering
        asm volatile("s_waitcnt lgkmcnt(0)" ::: "memory");
        __builtin_amdgcn_sched_barrier(0);

        // ---------------- GEMM2: a2 @ w2 ----------------
        f32x4 acc2[2][8];
        #pragma unroll
        for (int mt = 0; mt < 2; ++mt)
            #pragma unroll
            for (int nt = 0; nt < 8; ++nt) acc2[mt][nt] = (f32x4){0.f, 0.f, 0.f, 0.f};
        #pragma unroll
        for (int kt2 = 0; kt2 < 4; ++kt2) {
            short8 af[2];
            #pragma unroll
            for (int mt = 0; mt < 2; ++mt)
                __builtin_memcpy(&af[mt], &a2[w][mt][kt2][srl][0], 16);
            #pragma unroll
            for (int nt = 0; nt < 8; ++nt) {
                const short8 bf = ((const short8*)w2f)[(kt2 * 8 + nt) * 64 + lane];
                #pragma unroll
                for (int mt = 0; mt < 2; ++mt)
                    acc2[mt][nt] = __builtin_amdgcn_mfma_f32_16x16x32_bf16(af[mt], bf, acc2[mt][nt], 0, 0, 0);
            }
        }

        // ---------------- epilogue 2: +b2, LN2, mask, pool (registers) ----------------
        {
            f32x4 e2[8];
            #pragma unroll
            for (int nt = 0; nt < 8; ++nt) e2[nt] = ecoef2[nt * 16 + c];
            #pragma unroll
            for (int mt = 0; mt < 2; ++mt) {
                if (!amt[mt]) continue;
                #pragma unroll
                for (int r = 0; r < 4; ++r) {
                    float v[8], s = 0.f, q = 0.f;
                    #pragma unroll
                    for (int nt = 0; nt < 8; ++nt) {
                        v[nt] = acc2[mt][nt][r] + e2[nt][0];
                        s += v[nt]; q = fmaf(v[nt], v[nt], q);
                    }
                    s = red16(s); q = red16(q);
                    const float mean = s * (1.f / 128.f);
                    const float var  = fmaxf(q * (1.f / 128.f) - mean * mean, 0.f);
                    const float rstd = rsqrtf(var + LN_EPS);
                    const int p = R0 + mt * 16 + 4 * g + r;
                    const float msk = (p < len) ? 1.f : 0.f;
                    #pragma unroll
                    for (int nt = 0; nt < 8; ++nt) {
                        const float y = fmaf((v[nt] - mean) * rstd, e2[nt][1], e2[nt][2]);
                        pool[nt] = fmaf(y, msk, pool[nt]);
                    }
                }
            }
        }
    }

    // wave-level pool reduce (over g groups), then cross-wave combine in LDS
    #pragma unroll
    for (int nt = 0; nt < 8; ++nt) {
        float tv = pool[nt];
        tv += __shfl_xor(tv, 16);
        tv += __shfl_xor(tv, 32);
        pool[nt] = tv;
    }
    if (g == 0) {
        #pragma unroll
        for (int nt = 0; nt < 8; ++nt) poolbuf[w][nt * 16 + c] = pool[nt];
    }
    __syncthreads();
    if (tid < 128) {
        const float s = poolbuf[0][tid] + poolbuf[1][tid] + poolbuf[2][tid] + poolbuf[3][tid];
        out[b * 128 + tid] = (len > 0) ? s / (float)len : 0.f;
    }
}

extern "C" void kernel_launch(void* const* d_in, const int* in_sizes, int n_in,
                              void* d_out, int out_size, void* d_ws, size_t ws_size,
                              hipStream_t stream) {
    const int*   tids    = (const int*)  d_in[0];
    const float* dates   = (const float*)d_in[1];
    const int*   lengths = (const int*)  d_in[2];
    const float* emb     = (const float*)d_in[3];
    const float* tp_w    = (const float*)d_in[4];
    const float* tp_b    = (const float*)d_in[5];
    const float* tp_lnw  = (const float*)d_in[6];
    const float* tp_lnb  = (const float*)d_in[7];
    const float* w1      = (const float*)d_in[8];
    const float* b1      = (const float*)d_in[9];
    const float* ln1w    = (const float*)d_in[10];
    const float* ln1b    = (const float*)d_in[11];
    const float* w2      = (const float*)d_in[12];
    const float* b2      = (const float*)d_in[13];
    const float* ln2w    = (const float*)d_in[14];
    const float* ln2b    = (const float*)d_in[15];
    float* out = (float*)d_out;

    const int B = in_sizes[2];
    const int L = in_sizes[0] / B;
    const int emb_pairs = in_sizes[3] / 2;

    hipLaunchKernelGGL(prep_kernel, dim3(32), dim3(256), 0, stream,
                       w1, w2, emb, tp_w, tp_b, (unsigned*)d_ws, emb_pairs);
    hipLaunchKernelGGL(encoder_mfma, dim3(B), dim3(256), 0, stream,
                       tids, dates, lengths, tp_w, tp_b, tp_lnw, tp_lnb,
                       b1, ln1w, ln1b, b2, ln2w, ln2b,
                       (const unsigned*)d_ws, out, L, emb_pairs);
}